// Round 1
// baseline (150.437 us; speedup 1.0000x reference)
//
#include <hip/hip_runtime.h>
#include <hip/hip_bf16.h>

// Problem constants (setup_inputs: B=64, S=1024, H=128, A=8, CTX_WIN=5, PAD=2)
#define S_DIM 1024
#define H_DIM 128
#define A_DIM 8
#define W_WIN 5

typedef unsigned int uint;
typedef unsigned short ushort;
typedef __attribute__((ext_vector_type(8))) short short8;   // 8 bf16 = 4 VGPRs
typedef __attribute__((ext_vector_type(4))) float f32x4;

union U128 { uint4 u; short8 s; };

__device__ __forceinline__ ushort f2bf(float f) {
    uint u = __float_as_uint(f);
    uint r = (u + 0x7fffu + ((u >> 16) & 1u)) >> 16;   // round-to-nearest-even
    return (ushort)r;
}

// ---------------------------------------------------------------------------
// K1 (widened): grid (8 h-chunks, 8 aspects) x 128 threads.
//   thread = (hl = t>>3: 16 rows, fo = t&7: 16-wide f slice)
//   Gt[a][w*128+h] = sum_f P[a,h,f] * E[a,f,w], bf16.
//   Per-thread load chain: 4 float4 (was 32) -> latency cut ~4x, 64 blocks.
//   Also zeroes the per-batch finisher counters (ws is poisoned each run).
// ---------------------------------------------------------------------------
__global__ __launch_bounds__(128) void k_g(const float* __restrict__ P,
                                           const float* __restrict__ We,
                                           ushort* __restrict__ Gt,
                                           int* __restrict__ done) {
    const int a  = blockIdx.y;       // 0..7
    const int hc = blockIdx.x;       // 0..7 (16-row chunk)
    const int t  = threadIdx.x;

    if (a == 0 && hc == 0 && t < 64) done[t] = 0;   // re-zero counters each launch

    __shared__ float Es[H_DIM * W_WIN];             // 2560 B: E[a] (f-major, w inner)
    __shared__ float red[16 * 8 * W_WIN];           // 2560 B: partials [hl][fo][w]
    for (int i = t; i < H_DIM * W_WIN; i += 128) Es[i] = We[a * (H_DIM * W_WIN) + i];
    __syncthreads();

    const int hl = t >> 3, fo = t & 7;
    const float* Pr = P + ((size_t)(a * H_DIM + hc * 16 + hl)) * H_DIM + fo * 16;
    float acc[W_WIN] = {0.f, 0.f, 0.f, 0.f, 0.f};
#pragma unroll
    for (int j4 = 0; j4 < 4; ++j4) {
        float4 pv = ((const float4*)Pr)[j4];
        float pj[4] = {pv.x, pv.y, pv.z, pv.w};
#pragma unroll
        for (int j = 0; j < 4; ++j) {
            const float* e = &Es[(fo * 16 + j4 * 4 + j) * W_WIN];
#pragma unroll
            for (int w = 0; w < W_WIN; ++w) acc[w] += pj[j] * e[w];
        }
    }
#pragma unroll
    for (int w = 0; w < W_WIN; ++w) red[(hl * 8 + fo) * W_WIN + w] = acc[w];
    __syncthreads();

    if (t < 80) {                     // 16 rows x 5 windows
        const int w = t >> 4, h2 = t & 15;
        float s = 0.f;
#pragma unroll
        for (int f8 = 0; f8 < 8; ++f8) s += red[(h2 * 8 + f8) * W_WIN + w];
        Gt[a * (W_WIN * H_DIM) + w * H_DIM + hc * 16 + h2] = f2bf(s);
    }
}

// ---------------------------------------------------------------------------
// K2: per (b, 64-s slice). LDS ~31.9 KB -> 5 blocks/CU. Phases B-E unchanged
// from the 91.8 us kernel. NEW: last-arriving block per batch b (device-scope
// atomic counter election, release/acquire __threadfence) performs the former
// k_final work for all 8 aspects of b -> third launch eliminated, reduction
// overlaps the main-phase tail.
// ---------------------------------------------------------------------------
#define CS 64
#define RROWS (CS + 4)        // 68
#define EPITCH 88             // el pitch (176 B: 16B-aligned, 2-way banks)
__global__ __launch_bounds__(256) void k_scores(const float* __restrict__ Din,
                                                const ushort* __restrict__ Gt,
                                                ushort* __restrict__ escore,
                                                float* __restrict__ numPart,
                                                float* __restrict__ Zpart,
                                                const float* __restrict__ P,
                                                float* __restrict__ attn,
                                                float* __restrict__ rep,
                                                int* __restrict__ done) {
    __shared__ uint4 Dl[RROWS * 16];      // 17408 B bf16 doc tile, XOR swizzle
    __shared__ uint4 Gl[9 * 80];          // 11520 B: 8 aspect rows + zero row
    __shared__ ushort el[16 * EPITCH];    // 2816 B  e as bf16, [a][s]
    __shared__ float Zw[32];
    __shared__ int lastFlag;
    const int b   = blockIdx.y;
    const int slc = blockIdx.x;           // 0..15
    const int s0  = slc * CS;
    const int t   = threadIdx.x;
    const float* Db = Din + (size_t)b * S_DIM * H_DIM;

    // --- stage doc rows [s0-2, s0+CS+2), bf16, 16B-chunk XOR swizzle ---
    for (int i = t; i < RROWS * 16; i += 256) {
        const int r = i >> 4, c = i & 15;
        const int gs = s0 - 2 + r;
        float4 va = make_float4(0.f, 0.f, 0.f, 0.f), vb = va;
        if (gs >= 0 && gs < S_DIM) {
            const float* p = Db + (size_t)gs * H_DIM + c * 8;
            va = ((const float4*)p)[0];
            vb = ((const float4*)p)[1];
        }
        uint4 q;
        q.x = (uint)f2bf(va.x) | ((uint)f2bf(va.y) << 16);
        q.y = (uint)f2bf(va.z) | ((uint)f2bf(va.w) << 16);
        q.z = (uint)f2bf(vb.x) | ((uint)f2bf(vb.y) << 16);
        q.w = (uint)f2bf(vb.z) | ((uint)f2bf(vb.w) << 16);
        Dl[r * 16 + (c ^ (r & 15))] = q;
    }
    // --- stage Gl: rows 0..7 = Gt aspects, row 8 = zeros; chunk XOR swizzle ---
    {
        const uint4* Gg = (const uint4*)Gt;
        for (int i = t; i < 9 * 80; i += 256) {
            const int n = i / 80, c = i - n * 80;
            uint4 v = make_uint4(0u, 0u, 0u, 0u);
            if (n < 8) v = Gg[n * 80 + c];
            Gl[n * 80 + ((c & ~15) | ((c & 15) ^ n))] = v;
        }
    }
    __syncthreads();

    const int lane = t & 63;
    const int wv   = t >> 6;          // wave id 0..3 -> m-tile (16 s-rows)
    const int lm   = lane & 15;
    const int lq   = lane >> 4;
    const int gr   = (lm < 8) ? lm : 8;   // Gl row (8 = shared zero row)

    // ---- Phase B: score MFMA (LDS-only inner loop) ----
    f32x4 acc0 = {0.f, 0.f, 0.f, 0.f};
#pragma unroll
    for (int kk = 0; kk < 20; ++kk) {
        const int w = kk >> 2;
        const int r0 = wv * 16 + lm + w;
        const int cidx = (kk & 3) * 4 + lq;
        const int gc = kk * 4 + lq;
        U128 av, bv;
        bv.u = Gl[gr * 80 + ((gc & ~15) | ((gc & 15) ^ gr))];
        av.u = Dl[r0 * 16 + (cidx ^ (r0 & 15))];
        acc0 = __builtin_amdgcn_mfma_f32_16x16x32_bf16(av.s, bv.s, acc0, 0, 0, 0);
    }

    // ---- Phase C: e = exp(score); escore bf16, el LDS, Z wave-partials ----
    float4 e0;
    e0.x = __expf(acc0.x); e0.y = __expf(acc0.y); e0.z = __expf(acc0.z); e0.w = __expf(acc0.w);
    uint2 d0;
    d0.x = (uint)f2bf(e0.x) | ((uint)f2bf(e0.y) << 16);
    d0.y = (uint)f2bf(e0.z) | ((uint)f2bf(e0.w) << 16);
    const int sb = wv * 16 + lq * 4;
    if (lm < A_DIM)
        *(uint2*)(escore + (((size_t)b * A_DIM + lm) << 10) + s0 + sb) = d0;
    *(uint2*)(&el[lm * EPITCH + sb]) = d0;   // rows a>=8 hold exp(0)=1: unused

    float es = e0.x + e0.y + e0.z + e0.w;
    es += __shfl_xor(es, 16);
    es += __shfl_xor(es, 32);
    if (lq == 0 && lm < A_DIM) Zw[wv * 8 + lm] = es;
    __syncthreads();

    // ---- Phase D: numerator MFMA  C[m=a][n=h], K=s=64 ----
    const ushort* Dls = (const ushort*)Dl;
    U128 afr[2];
#pragma unroll
    for (int kk = 0; kk < 2; ++kk)
        afr[kk].u = *(const uint4*)(&el[lm * EPITCH + kk * 32 + lq * 8]);

    f32x4 accN[2] = {{0.f,0.f,0.f,0.f},{0.f,0.f,0.f,0.f}};
#pragma unroll
    for (int nt = 0; nt < 2; ++nt) {
        const int h  = wv * 32 + nt * 16 + lm;
        const int ch = h >> 3, hw = h & 7;
#pragma unroll
        for (int kk = 0; kk < 2; ++kk) {
            uint p[4];
#pragma unroll
            for (int jj = 0; jj < 4; ++jj) {
                const int sj = kk * 32 + lq * 8 + jj * 2;
                const int ra = sj + 2, rb = sj + 3;   // +2 halo offset
                const uint lo = Dls[(ra * 16 + (ch ^ (ra & 15))) * 8 + hw];
                const uint hi = Dls[(rb * 16 + (ch ^ (rb & 15))) * 8 + hw];
                p[jj] = lo | (hi << 16);
            }
            U128 bfr; bfr.u = make_uint4(p[0], p[1], p[2], p[3]);
            accN[nt] = __builtin_amdgcn_mfma_f32_16x16x32_bf16(afr[kk].s, bfr.s, accN[nt], 0, 0, 0);
        }
    }

    // ---- Phase E: per-slice partials, pure stores ----
    if (lq < 2) {   // C rows m = lq*4+r = aspect 0..7
#pragma unroll
        for (int nt = 0; nt < 2; ++nt) {
            const int h = wv * 32 + nt * 16 + lm;
#pragma unroll
            for (int r = 0; r < 4; ++r)
                numPart[(((size_t)(b * 16 + slc) * 8) + lq * 4 + r) * H_DIM + h] = accN[nt][r];
        }
    }
    if (t < A_DIM)
        Zpart[(b * 16 + slc) * 8 + t] = Zw[t] + Zw[8 + t] + Zw[16 + t] + Zw[24 + t];

    // ---- Finisher election: 16th arriver for batch b does the reduction ----
    __syncthreads();                       // all stores issued (vmcnt drained)
    if (t == 0) {
        __threadfence();                   // release: writeback L2 (cross-XCD)
        lastFlag = (atomicAdd(&done[b], 1) == 15);
    }
    __syncthreads();
    if (!lastFlag) return;
    __threadfence();                       // acquire: invalidate stale L1/L2

    // ---- Former k_final, all 8 aspects of this b, 256 threads ----
    float* fs = (float*)Dl;                // reuse doc tile: 1024 num sums
    float* Zf = (float*)Gl;                // reuse: 8 x (1/Z)
    if (t < A_DIM) {
        float z = 0.f;
#pragma unroll
        for (int k = 0; k < 16; ++k) z += Zpart[(b * 16 + k) * 8 + t];
        Zf[t] = 1.0f / z;
    }
    for (int i = t; i < A_DIM * H_DIM; i += 256) {
        float s = 0.f;
#pragma unroll
        for (int k = 0; k < 16; ++k)
            s += numPart[(((size_t)(b * 16 + k) * 8) + (i >> 7)) * H_DIM + (i & 127)];
        fs[i] = s;
    }
    __syncthreads();

    // attn = escore * (1/Z): 8 aspects x 1024 s = 2048 uint2 units
    for (int i = t; i < (A_DIM * S_DIM) / 4; i += 256) {
        const int a2 = i >> 8;                       // 256 uint2 per aspect row
        const float rz = Zf[a2];
        const size_t off = (((size_t)b * 8 + a2) << 10) + ((i & 255) << 2);
        uint2 q = *(const uint2*)(escore + off);
        float4 v;
        v.x = __uint_as_float(q.x << 16) * rz;
        v.y = __uint_as_float(q.x & 0xffff0000u) * rz;
        v.z = __uint_as_float(q.y << 16) * rz;
        v.w = __uint_as_float(q.y & 0xffff0000u) * rz;
        *(float4*)(attn + off) = v;
    }

    // rep[b,a,f] = (1/Z) * sum_h fs[a,h] * P[a,h,f]
    for (int i = t; i < A_DIM * H_DIM; i += 256) {
        const int a2 = i >> 7, f = i & 127;
        const float* Pa = P + (size_t)a2 * H_DIM * H_DIM + f;
        float acc = 0.f;
#pragma unroll 16
        for (int hh = 0; hh < H_DIM; ++hh)
            acc += fs[(a2 << 7) + hh] * Pa[(size_t)hh * H_DIM];
        rep[(((size_t)b * 8 + a2)) * H_DIM + f] = acc * Zf[a2];
    }
}

// ---------------------------------------------------------------------------
extern "C" void kernel_launch(void* const* d_in, const int* in_sizes, int n_in,
                              void* d_out, int out_size, void* d_ws, size_t ws_size,
                              hipStream_t stream) {
    const float* docIn = (const float*)d_in[0];   // (B, S, H) fp32
    const float* We    = (const float*)d_in[1];   // (A, 5*H)  fp32
    const float* P     = (const float*)d_in[2];   // (A, H, H) fp32
    float* out = (float*)d_out;                   // [B*A*S attn | B*A*H rep]

    const int B = in_sizes[0] / (S_DIM * H_DIM);  // 64

    ushort* Gt     = (ushort*)d_ws;                                   // 20 KB
    int*    done   = (int*)((char*)d_ws + 20480);                     // 64 counters
    ushort* escore = (ushort*)((char*)d_ws + 32768);                  // B*A*S bf16 = 1 MB
    float* numPart = (float*)((char*)d_ws + 32768 +
                              (size_t)B * A_DIM * S_DIM * 2);         // B*16*8*H
    float* Zpart   = numPart + (size_t)B * 16 * 8 * H_DIM;            // B*16*8

    k_g<<<dim3(8, 8), 128, 0, stream>>>(P, We, Gt, done);
    k_scores<<<dim3(S_DIM / CS, B), 256, 0, stream>>>(docIn, Gt, escore, numPart, Zpart,
                                                      P, out,
                                                      out + (size_t)B * A_DIM * S_DIM,
                                                      done);
}

// Round 2
// 89.104 us; speedup vs baseline: 1.6883x; 1.6883x over previous
//
#include <hip/hip_runtime.h>
#include <hip/hip_bf16.h>

// Problem constants (setup_inputs: B=64, S=1024, H=128, A=8, CTX_WIN=5, PAD=2)
#define S_DIM 1024
#define H_DIM 128
#define A_DIM 8
#define W_WIN 5

typedef unsigned int uint;
typedef unsigned short ushort;
typedef __attribute__((ext_vector_type(8))) short short8;   // 8 bf16 = 4 VGPRs
typedef __attribute__((ext_vector_type(4))) float f32x4;

union U128 { uint4 u; short8 s; };

__device__ __forceinline__ ushort f2bf(float f) {
    uint u = __float_as_uint(f);
    uint r = (u + 0x7fffu + ((u >> 16) & 1u)) >> 16;   // round-to-nearest-even
    return (ushort)r;
}

// ---------------------------------------------------------------------------
// K1 (widened): grid (8 h-chunks, 8 aspects) x 128 threads.
//   Gt[a][w*128+h] = sum_f P[a,h,f] * E[a,f,w], bf16.
//   Per-thread load chain: 4 float4 -> latency cut 8x vs original 16-block form.
// ---------------------------------------------------------------------------
__global__ __launch_bounds__(128) void k_g(const float* __restrict__ P,
                                           const float* __restrict__ We,
                                           ushort* __restrict__ Gt) {
    const int a  = blockIdx.y;       // 0..7
    const int hc = blockIdx.x;       // 0..7 (16-row chunk)
    const int t  = threadIdx.x;

    __shared__ float Es[H_DIM * W_WIN];             // 2560 B: E[a] (f-major, w inner)
    __shared__ float red[16 * 8 * W_WIN];           // 2560 B: partials [hl][fo][w]
    for (int i = t; i < H_DIM * W_WIN; i += 128) Es[i] = We[a * (H_DIM * W_WIN) + i];
    __syncthreads();

    const int hl = t >> 3, fo = t & 7;
    const float* Pr = P + ((size_t)(a * H_DIM + hc * 16 + hl)) * H_DIM + fo * 16;
    float acc[W_WIN] = {0.f, 0.f, 0.f, 0.f, 0.f};
#pragma unroll
    for (int j4 = 0; j4 < 4; ++j4) {
        float4 pv = ((const float4*)Pr)[j4];
        float pj[4] = {pv.x, pv.y, pv.z, pv.w};
#pragma unroll
        for (int j = 0; j < 4; ++j) {
            const float* e = &Es[(fo * 16 + j4 * 4 + j) * W_WIN];
#pragma unroll
            for (int w = 0; w < W_WIN; ++w) acc[w] += pj[j] * e[w];
        }
    }
#pragma unroll
    for (int w = 0; w < W_WIN; ++w) red[(hl * 8 + fo) * W_WIN + w] = acc[w];
    __syncthreads();

    if (t < 80) {                     // 16 rows x 5 windows
        const int w = t >> 4, h2 = t & 15;
        float s = 0.f;
#pragma unroll
        for (int f8 = 0; f8 < 8; ++f8) s += red[(h2 * 8 + f8) * W_WIN + w];
        Gt[a * (W_WIN * H_DIM) + w * H_DIM + hc * 16 + h2] = f2bf(s);
    }
}

// ---------------------------------------------------------------------------
// K2: per (b, 64-s slice). LDS 31.9 KB -> blocks fully co-resident (4/CU).
// No device-scope fences (R1 lesson: per-block buffer_wbl2 is catastrophic);
// cross-kernel visibility via kernel boundary only.
// Staging rewritten for ILP: each thread = fixed column c=t&15, rows
// (t>>4)+{0,16,32,48}(+64): all float4 loads issued unconditionally with
// clamped addresses (8-10 in flight), masked after, then converted+ds_write.
// ---------------------------------------------------------------------------
#define CS 64
#define RROWS (CS + 4)        // 68
#define EPITCH 88             // el pitch (176 B: 16B-aligned, 2-way banks)
__global__ __launch_bounds__(256) void k_scores(const float* __restrict__ Din,
                                                const ushort* __restrict__ Gt,
                                                ushort* __restrict__ escore,
                                                float* __restrict__ numPart,
                                                float* __restrict__ Zpart) {
    __shared__ uint4 Dl[RROWS * 16];      // 17408 B bf16 doc tile, XOR swizzle
    __shared__ uint4 Gl[9 * 80];          // 11520 B: 8 aspect rows + zero row
    __shared__ ushort el[16 * EPITCH];    // 2816 B  e as bf16, [a][s]
    __shared__ float Zw[32];
    const int b   = blockIdx.y;
    const int slc = blockIdx.x;           // 0..15
    const int s0  = slc * CS;
    const int t   = threadIdx.x;
    const float* Db = Din + (size_t)b * S_DIM * H_DIM;

    // --- stage doc rows [s0-2, s0+CS+2): issue-all-loads-first for ILP ---
    {
        const int c  = t & 15;
        const int r0 = t >> 4;
        float4 va[5], vb[5];
        bool ok[5];
#pragma unroll
        for (int k = 0; k < 4; ++k) {
            const int gs = s0 - 2 + r0 + k * 16;
            ok[k] = (gs >= 0) && (gs < S_DIM);
            const int gc = min(max(gs, 0), S_DIM - 1);
            const float4* p = (const float4*)(Db + (size_t)gc * H_DIM + c * 8);
            va[k] = p[0];
            vb[k] = p[1];
        }
        if (t < 64) {                              // tail rows 64..67
            const int gs = s0 - 2 + 64 + r0;
            ok[4] = (gs >= 0) && (gs < S_DIM);
            const int gc = min(max(gs, 0), S_DIM - 1);
            const float4* p = (const float4*)(Db + (size_t)gc * H_DIM + c * 8);
            va[4] = p[0];
            vb[4] = p[1];
        }
#pragma unroll
        for (int k = 0; k < 5; ++k) {
            if (k == 4 && t >= 64) break;
            const int r = (k == 4) ? (64 + r0) : (r0 + k * 16);
            float4 A = va[k], Bv = vb[k];
            if (!ok[k]) { A = make_float4(0.f,0.f,0.f,0.f); Bv = A; }
            uint4 q;
            q.x = (uint)f2bf(A.x)  | ((uint)f2bf(A.y)  << 16);
            q.y = (uint)f2bf(A.z)  | ((uint)f2bf(A.w)  << 16);
            q.z = (uint)f2bf(Bv.x) | ((uint)f2bf(Bv.y) << 16);
            q.w = (uint)f2bf(Bv.z) | ((uint)f2bf(Bv.w) << 16);
            Dl[r * 16 + (c ^ (r & 15))] = q;
        }
    }
    // --- stage Gl: rows 0..7 = Gt aspects, row 8 = zeros; chunk XOR swizzle ---
    {
        const uint4* Gg = (const uint4*)Gt;
        for (int i = t; i < 9 * 80; i += 256) {
            const int n = i / 80, c = i - n * 80;
            uint4 v = make_uint4(0u, 0u, 0u, 0u);
            if (n < 8) v = Gg[n * 80 + c];
            Gl[n * 80 + ((c & ~15) | ((c & 15) ^ n))] = v;
        }
    }
    __syncthreads();

    const int lane = t & 63;
    const int wv   = t >> 6;          // wave id 0..3 -> m-tile (16 s-rows)
    const int lm   = lane & 15;
    const int lq   = lane >> 4;
    const int gr   = (lm < 8) ? lm : 8;   // Gl row (8 = shared zero row)

    // ---- Phase B: score MFMA (LDS-only inner loop) ----
    f32x4 acc0 = {0.f, 0.f, 0.f, 0.f};
#pragma unroll
    for (int kk = 0; kk < 20; ++kk) {
        const int w = kk >> 2;
        const int r0 = wv * 16 + lm + w;
        const int cidx = (kk & 3) * 4 + lq;
        const int gc = kk * 4 + lq;
        U128 av, bv;
        bv.u = Gl[gr * 80 + ((gc & ~15) | ((gc & 15) ^ gr))];
        av.u = Dl[r0 * 16 + (cidx ^ (r0 & 15))];
        acc0 = __builtin_amdgcn_mfma_f32_16x16x32_bf16(av.s, bv.s, acc0, 0, 0, 0);
    }

    // ---- Phase C: e = exp(score); escore bf16, el LDS, Z wave-partials ----
    float4 e0;
    e0.x = __expf(acc0.x); e0.y = __expf(acc0.y); e0.z = __expf(acc0.z); e0.w = __expf(acc0.w);
    uint2 d0;
    d0.x = (uint)f2bf(e0.x) | ((uint)f2bf(e0.y) << 16);
    d0.y = (uint)f2bf(e0.z) | ((uint)f2bf(e0.w) << 16);
    const int sb = wv * 16 + lq * 4;
    if (lm < A_DIM)
        *(uint2*)(escore + (((size_t)b * A_DIM + lm) << 10) + s0 + sb) = d0;
    *(uint2*)(&el[lm * EPITCH + sb]) = d0;   // rows a>=8 hold exp(0)=1: unused

    float es = e0.x + e0.y + e0.z + e0.w;
    es += __shfl_xor(es, 16);
    es += __shfl_xor(es, 32);
    if (lq == 0 && lm < A_DIM) Zw[wv * 8 + lm] = es;
    __syncthreads();

    // ---- Phase D: numerator MFMA  C[m=a][n=h], K=s=64 ----
    const ushort* Dls = (const ushort*)Dl;
    U128 afr[2];
#pragma unroll
    for (int kk = 0; kk < 2; ++kk)
        afr[kk].u = *(const uint4*)(&el[lm * EPITCH + kk * 32 + lq * 8]);

    f32x4 accN[2] = {{0.f,0.f,0.f,0.f},{0.f,0.f,0.f,0.f}};
#pragma unroll
    for (int nt = 0; nt < 2; ++nt) {
        const int h  = wv * 32 + nt * 16 + lm;
        const int ch = h >> 3, hw = h & 7;
#pragma unroll
        for (int kk = 0; kk < 2; ++kk) {
            uint p[4];
#pragma unroll
            for (int jj = 0; jj < 4; ++jj) {
                const int sj = kk * 32 + lq * 8 + jj * 2;
                const int ra = sj + 2, rb = sj + 3;   // +2 halo offset
                const uint lo = Dls[(ra * 16 + (ch ^ (ra & 15))) * 8 + hw];
                const uint hi = Dls[(rb * 16 + (ch ^ (rb & 15))) * 8 + hw];
                p[jj] = lo | (hi << 16);
            }
            U128 bfr; bfr.u = make_uint4(p[0], p[1], p[2], p[3]);
            accN[nt] = __builtin_amdgcn_mfma_f32_16x16x32_bf16(afr[kk].s, bfr.s, accN[nt], 0, 0, 0);
        }
    }

    // ---- Phase E: per-slice partials, pure stores ----
    if (lq < 2) {   // C rows m = lq*4+r = aspect 0..7
#pragma unroll
        for (int nt = 0; nt < 2; ++nt) {
            const int h = wv * 32 + nt * 16 + lm;
#pragma unroll
            for (int r = 0; r < 4; ++r)
                numPart[(((size_t)(b * 16 + slc) * 8) + lq * 4 + r) * H_DIM + h] = accN[nt][r];
        }
    }
    if (t < A_DIM)
        Zpart[(b * 16 + slc) * 8 + t] = Zw[t] + Zw[8 + t] + Zw[16 + t] + Zw[24 + t];
}

// ---------------------------------------------------------------------------
// K3 (widened): grid (2 halves, B*A) x 128. Each block: full Z + ws reduce,
// attn for half the s-range, rep for half the f-range with split-K over the
// two waves (LDS combine). 2x blocks vs round-0 -> latency tail halved.
// ---------------------------------------------------------------------------
__global__ __launch_bounds__(128) void k_final(const ushort* __restrict__ escore,
                                               const float* __restrict__ numPart,
                                               const float* __restrict__ Zpart,
                                               const float* __restrict__ P,
                                               float* __restrict__ attn,
                                               float* __restrict__ rep) {
    __shared__ float ws[H_DIM];
    __shared__ float par[128];
    const int ba = blockIdx.y;                // b*8 + a
    const int hf = blockIdx.x;                // 0..1
    const int b = ba >> 3, a = ba & 7;
    const int t = threadIdx.x;

    float Zs = 0.f;
#pragma unroll
    for (int k = 0; k < 16; ++k) Zs += Zpart[(b * 16 + k) * 8 + a];
    const float rz = 1.0f / Zs;

    float s = 0.f;
#pragma unroll
    for (int k = 0; k < 16; ++k)
        s += numPart[(((size_t)(b * 16 + k) * 8) + a) * H_DIM + t];
    ws[t] = s * rz;

    // attn for s-range [hf*512, hf*512+512)
    const ushort* ep = escore + (size_t)ba * S_DIM;
    float* ap = attn + (size_t)ba * S_DIM;
    {
        uint2 q = *(const uint2*)(ep + hf * 512 + t * 4);
        float4 v;
        v.x = __uint_as_float(q.x << 16) * rz;
        v.y = __uint_as_float(q.x & 0xffff0000u) * rz;
        v.z = __uint_as_float(q.y << 16) * rz;
        v.w = __uint_as_float(q.y & 0xffff0000u) * rz;
        *(float4*)(ap + hf * 512 + t * 4) = v;
    }
    __syncthreads();

    // rep[f] for f in [hf*64, hf*64+64): split-K across the two waves
    const int f  = hf * 64 + (t & 63);
    const int h0 = (t >> 6) * 64;
    const float* Pa = P + (size_t)a * H_DIM * H_DIM + f;
    float acc = 0.f;
#pragma unroll 16
    for (int hh = 0; hh < 64; ++hh)
        acc += ws[h0 + hh] * Pa[(size_t)(h0 + hh) * H_DIM];
    par[t] = acc;
    __syncthreads();
    if (t < 64)
        rep[(size_t)ba * H_DIM + f] = par[t] + par[t + 64];
}

// ---------------------------------------------------------------------------
extern "C" void kernel_launch(void* const* d_in, const int* in_sizes, int n_in,
                              void* d_out, int out_size, void* d_ws, size_t ws_size,
                              hipStream_t stream) {
    const float* docIn = (const float*)d_in[0];   // (B, S, H) fp32
    const float* We    = (const float*)d_in[1];   // (A, 5*H)  fp32
    const float* P     = (const float*)d_in[2];   // (A, H, H) fp32
    float* out = (float*)d_out;                   // [B*A*S attn | B*A*H rep]

    const int B = in_sizes[0] / (S_DIM * H_DIM);  // 64

    ushort* Gt     = (ushort*)d_ws;                                   // 10 KB
    ushort* escore = (ushort*)((char*)d_ws + 32768);                  // B*A*S bf16 = 1 MB
    float* numPart = (float*)((char*)d_ws + 32768 +
                              (size_t)B * A_DIM * S_DIM * 2);         // B*16*8*H
    float* Zpart   = numPart + (size_t)B * 16 * 8 * H_DIM;            // B*16*8

    k_g<<<dim3(8, 8), 128, 0, stream>>>(P, We, Gt);
    k_scores<<<dim3(S_DIM / CS, B), 256, 0, stream>>>(docIn, Gt, escore, numPart, Zpart);
    k_final<<<dim3(2, B * A_DIM), 128, 0, stream>>>(escore, numPart, Zpart, P, out,
                                                    out + (size_t)B * A_DIM * S_DIM);
}

// Round 3
// 87.565 us; speedup vs baseline: 1.7180x; 1.0176x over previous
//
#include <hip/hip_runtime.h>
#include <hip/hip_bf16.h>

// Problem constants (setup_inputs: B=64, S=1024, H=128, A=8, CTX_WIN=5, PAD=2)
#define S_DIM 1024
#define H_DIM 128
#define A_DIM 8
#define W_WIN 5

typedef unsigned int uint;
typedef unsigned short ushort;
typedef __attribute__((ext_vector_type(8))) short short8;   // 8 bf16 = 4 VGPRs
typedef __attribute__((ext_vector_type(4))) float f32x4;

union U128 { uint4 u; short8 s; };

__device__ __forceinline__ ushort f2bf(float f) {
    uint u = __float_as_uint(f);
    uint r = (u + 0x7fffu + ((u >> 16) & 1u)) >> 16;   // round-to-nearest-even
    return (ushort)r;
}

// ---------------------------------------------------------------------------
// K1: grid (8 h-chunks, 8 aspects) x 128 threads.
//   Gt[a][w*128+h] = sum_f P[a,h,f] * E[a,f,w], bf16. 4-deep load chain.
// ---------------------------------------------------------------------------
__global__ __launch_bounds__(128) void k_g(const float* __restrict__ P,
                                           const float* __restrict__ We,
                                           ushort* __restrict__ Gt) {
    const int a  = blockIdx.y;       // 0..7
    const int hc = blockIdx.x;       // 0..7 (16-row chunk)
    const int t  = threadIdx.x;

    __shared__ float Es[H_DIM * W_WIN];             // 2560 B: E[a] (f-major, w inner)
    __shared__ float red[16 * 8 * W_WIN];           // 2560 B: partials [hl][fo][w]
    for (int i = t; i < H_DIM * W_WIN; i += 128) Es[i] = We[a * (H_DIM * W_WIN) + i];
    __syncthreads();

    const int hl = t >> 3, fo = t & 7;
    const float* Pr = P + ((size_t)(a * H_DIM + hc * 16 + hl)) * H_DIM + fo * 16;
    float acc[W_WIN] = {0.f, 0.f, 0.f, 0.f, 0.f};
#pragma unroll
    for (int j4 = 0; j4 < 4; ++j4) {
        float4 pv = ((const float4*)Pr)[j4];
        float pj[4] = {pv.x, pv.y, pv.z, pv.w};
#pragma unroll
        for (int j = 0; j < 4; ++j) {
            const float* e = &Es[(fo * 16 + j4 * 4 + j) * W_WIN];
#pragma unroll
            for (int w = 0; w < W_WIN; ++w) acc[w] += pj[j] * e[w];
        }
    }
#pragma unroll
    for (int w = 0; w < W_WIN; ++w) red[(hl * 8 + fo) * W_WIN + w] = acc[w];
    __syncthreads();

    if (t < 80) {                     // 16 rows x 5 windows
        const int w = t >> 4, h2 = t & 15;
        float s = 0.f;
#pragma unroll
        for (int f8 = 0; f8 < 8; ++f8) s += red[(h2 * 8 + f8) * W_WIN + w];
        Gt[a * (W_WIN * H_DIM) + w * H_DIM + hc * 16 + h2] = f2bf(s);
    }
}

// ---------------------------------------------------------------------------
// K2: CS=128, 512 threads (8 waves), 512 blocks. LDS 48.8 KB -> 3 blocks/CU
// = 24 waves/CU (was 16). Fewer, fatter blocks: halo & Gl re-staging halve,
// 200 MFMA/block. No device-scope fences (R1 lesson).
//  B: score[s(128)][a(16)] MFMA over K=640
//  C: e=exp(score) -> escore global bf16, el LDS, Zw wave-partials
//  D: num[a(16)][h(128)] = sum_{s=0..127} e*doc, K=128 (4 MFMA chain)
//  E: per-slice partial stores (8 slices per b now)
// ---------------------------------------------------------------------------
#define CS 128
#define RROWS (CS + 4)        // 132
#define EPITCH 136            // el pitch bf16 (272 B: 16B-aligned)
__global__ __launch_bounds__(512) void k_scores(const float* __restrict__ Din,
                                                const ushort* __restrict__ Gt,
                                                ushort* __restrict__ escore,
                                                float* __restrict__ numPart,
                                                float* __restrict__ Zpart) {
    __shared__ uint4 Dl[RROWS * 16];      // 33792 B bf16 doc tile, XOR swizzle
    __shared__ uint4 Gl[9 * 80];          // 11520 B: 8 aspect rows + zero row
    __shared__ ushort el[16 * EPITCH];    // 4352 B  e as bf16, [a][s]
    __shared__ float Zw[64];              // 8 waves x 8 aspects
    const int b   = blockIdx.y;
    const int slc = blockIdx.x;           // 0..7
    const int s0  = slc * CS;
    const int t   = threadIdx.x;
    const float* Db = Din + (size_t)b * S_DIM * H_DIM;

    // --- stage doc rows [s0-2, s0+CS+2): issue-all-loads-first for ILP ---
    {
        const int c  = t & 15;
        const int r0 = t >> 4;            // 0..31
        float4 va[5], vb[5];
        bool ok[5];
#pragma unroll
        for (int k = 0; k < 4; ++k) {
            const int gs = s0 - 2 + r0 + k * 32;
            ok[k] = (gs >= 0) && (gs < S_DIM);
            const int gc = min(max(gs, 0), S_DIM - 1);
            const float4* p = (const float4*)(Db + (size_t)gc * H_DIM + c * 8);
            va[k] = p[0];
            vb[k] = p[1];
        }
        if (t < 64) {                              // tail rows 128..131
            const int gs = s0 - 2 + 128 + r0;
            ok[4] = (gs >= 0) && (gs < S_DIM);
            const int gc = min(max(gs, 0), S_DIM - 1);
            const float4* p = (const float4*)(Db + (size_t)gc * H_DIM + c * 8);
            va[4] = p[0];
            vb[4] = p[1];
        }
#pragma unroll
        for (int k = 0; k < 5; ++k) {
            if (k == 4 && t >= 64) break;
            const int r = (k == 4) ? (128 + r0) : (r0 + k * 32);
            float4 A = va[k], Bv = vb[k];
            if (!ok[k]) { A = make_float4(0.f,0.f,0.f,0.f); Bv = A; }
            uint4 q;
            q.x = (uint)f2bf(A.x)  | ((uint)f2bf(A.y)  << 16);
            q.y = (uint)f2bf(A.z)  | ((uint)f2bf(A.w)  << 16);
            q.z = (uint)f2bf(Bv.x) | ((uint)f2bf(Bv.y) << 16);
            q.w = (uint)f2bf(Bv.z) | ((uint)f2bf(Bv.w) << 16);
            Dl[r * 16 + (c ^ (r & 15))] = q;
        }
    }
    // --- stage Gl: rows 0..7 = Gt aspects, row 8 = zeros; chunk XOR swizzle ---
    {
        const uint4* Gg = (const uint4*)Gt;
        for (int i = t; i < 9 * 80; i += 512) {
            const int n = i / 80, c = i - n * 80;
            uint4 v = make_uint4(0u, 0u, 0u, 0u);
            if (n < 8) v = Gg[n * 80 + c];
            Gl[n * 80 + ((c & ~15) | ((c & 15) ^ n))] = v;
        }
    }
    __syncthreads();

    const int lane = t & 63;
    const int wv   = t >> 6;          // wave id 0..7 -> m-tile (16 s-rows)
    const int lm   = lane & 15;
    const int lq   = lane >> 4;
    const int gr   = (lm < 8) ? lm : 8;   // Gl row (8 = shared zero row)

    // ---- Phase B: score MFMA (LDS-only inner loop) ----
    f32x4 acc0 = {0.f, 0.f, 0.f, 0.f};
#pragma unroll
    for (int kk = 0; kk < 20; ++kk) {
        const int w = kk >> 2;
        const int r0 = wv * 16 + lm + w;          // <= 131
        const int cidx = (kk & 3) * 4 + lq;
        const int gc = kk * 4 + lq;
        U128 av, bv;
        bv.u = Gl[gr * 80 + ((gc & ~15) | ((gc & 15) ^ gr))];
        av.u = Dl[r0 * 16 + (cidx ^ (r0 & 15))];
        acc0 = __builtin_amdgcn_mfma_f32_16x16x32_bf16(av.s, bv.s, acc0, 0, 0, 0);
    }

    // ---- Phase C: e = exp(score); escore bf16, el LDS, Z wave-partials ----
    // C layout: col(a)=lm, rows s = wv*16 + lq*4 + r
    float4 e0;
    e0.x = __expf(acc0.x); e0.y = __expf(acc0.y); e0.z = __expf(acc0.z); e0.w = __expf(acc0.w);
    uint2 d0;
    d0.x = (uint)f2bf(e0.x) | ((uint)f2bf(e0.y) << 16);
    d0.y = (uint)f2bf(e0.z) | ((uint)f2bf(e0.w) << 16);
    const int sb = wv * 16 + lq * 4;              // 0..124
    if (lm < A_DIM)
        *(uint2*)(escore + (((size_t)b * A_DIM + lm) << 10) + s0 + sb) = d0;
    *(uint2*)(&el[lm * EPITCH + sb]) = d0;   // rows a>=8 hold exp(0)=1: unused

    float es = e0.x + e0.y + e0.z + e0.w;
    es += __shfl_xor(es, 16);
    es += __shfl_xor(es, 32);
    if (lq == 0 && lm < A_DIM) Zw[wv * 8 + lm] = es;
    __syncthreads();

    // ---- Phase D: numerator MFMA  C[m=a][n=h], K=s=128 (4-chain) ----
    const ushort* Dls = (const ushort*)Dl;
    U128 afr[4];
#pragma unroll
    for (int kk = 0; kk < 4; ++kk)
        afr[kk].u = *(const uint4*)(&el[lm * EPITCH + kk * 32 + lq * 8]);

    f32x4 accN = {0.f, 0.f, 0.f, 0.f};
    {
        const int h  = wv * 16 + lm;              // 0..127
        const int ch = h >> 3, hw = h & 7;
#pragma unroll
        for (int kk = 0; kk < 4; ++kk) {
            uint p[4];
#pragma unroll
            for (int jj = 0; jj < 4; ++jj) {
                const int sj = kk * 32 + lq * 8 + jj * 2;
                const int ra = sj + 2, rb = sj + 3;   // +2 halo offset, <=129
                const uint lo = Dls[(ra * 16 + (ch ^ (ra & 15))) * 8 + hw];
                const uint hi = Dls[(rb * 16 + (ch ^ (rb & 15))) * 8 + hw];
                p[jj] = lo | (hi << 16);
            }
            U128 bfr; bfr.u = make_uint4(p[0], p[1], p[2], p[3]);
            accN = __builtin_amdgcn_mfma_f32_16x16x32_bf16(afr[kk].s, bfr.s, accN, 0, 0, 0);
        }
    }

    // ---- Phase E: per-slice partials, pure stores (8 slices per b) ----
    if (lq < 2) {   // C rows m = lq*4+r = aspect 0..7
        const int h = wv * 16 + lm;
#pragma unroll
        for (int r = 0; r < 4; ++r)
            numPart[(((size_t)(b * 8 + slc) * 8) + lq * 4 + r) * H_DIM + h] = accN[r];
    }
    if (t < A_DIM) {
        float z = 0.f;
#pragma unroll
        for (int k = 0; k < 8; ++k) z += Zw[k * 8 + t];
        Zpart[(b * 8 + slc) * 8 + t] = z;
    }
}

// ---------------------------------------------------------------------------
// K3: per (b,a): Z = sum Zpart; attn = escore/Z; wsum[h] = sum numPart / Z;
//     rep[b,a,f] = sum_h wsum[h]*P[a,h,f]. 8 slices now (half the reduce).
// ---------------------------------------------------------------------------
__global__ __launch_bounds__(128) void k_final(const ushort* __restrict__ escore,
                                               const float* __restrict__ numPart,
                                               const float* __restrict__ Zpart,
                                               const float* __restrict__ P,
                                               float* __restrict__ attn,
                                               float* __restrict__ rep) {
    __shared__ float ws[H_DIM];
    const int ba = blockIdx.x;                // b*8 + a
    const int b = ba >> 3, a = ba & 7;
    const int t = threadIdx.x;

    float Zs = 0.f;
#pragma unroll
    for (int k = 0; k < 8; ++k) Zs += Zpart[(b * 8 + k) * 8 + a];
    const float rz = 1.0f / Zs;

    float s = 0.f;
#pragma unroll
    for (int k = 0; k < 8; ++k)
        s += numPart[(((size_t)(b * 8 + k) * 8) + a) * H_DIM + t];
    ws[t] = s * rz;

    const ushort* ep = escore + (size_t)ba * S_DIM;
    float* ap = attn + (size_t)ba * S_DIM;
#pragma unroll
    for (int i = 0; i < 2; ++i) {
        uint2 q = *(const uint2*)(ep + i * 512 + t * 4);
        float4 v;
        v.x = __uint_as_float(q.x << 16) * rz;
        v.y = __uint_as_float(q.x & 0xffff0000u) * rz;
        v.z = __uint_as_float(q.y << 16) * rz;
        v.w = __uint_as_float(q.y & 0xffff0000u) * rz;
        *(float4*)(ap + i * 512 + t * 4) = v;
    }
    __syncthreads();

    const float* Pa = P + (size_t)a * H_DIM * H_DIM + t;
    float acc = 0.f;
#pragma unroll 32
    for (int hh = 0; hh < H_DIM; ++hh)
        acc += ws[hh] * Pa[(size_t)hh * H_DIM];
    rep[(size_t)ba * H_DIM + t] = acc;
}

// ---------------------------------------------------------------------------
extern "C" void kernel_launch(void* const* d_in, const int* in_sizes, int n_in,
                              void* d_out, int out_size, void* d_ws, size_t ws_size,
                              hipStream_t stream) {
    const float* docIn = (const float*)d_in[0];   // (B, S, H) fp32
    const float* We    = (const float*)d_in[1];   // (A, 5*H)  fp32
    const float* P     = (const float*)d_in[2];   // (A, H, H) fp32
    float* out = (float*)d_out;                   // [B*A*S attn | B*A*H rep]

    const int B = in_sizes[0] / (S_DIM * H_DIM);  // 64

    ushort* Gt     = (ushort*)d_ws;                                   // 10 KB
    ushort* escore = (ushort*)((char*)d_ws + 32768);                  // B*A*S bf16 = 1 MB
    float* numPart = (float*)((char*)d_ws + 32768 +
                              (size_t)B * A_DIM * S_DIM * 2);         // B*8*8*H = 2 MB
    float* Zpart   = numPart + (size_t)B * 8 * 8 * H_DIM;             // B*8*8

    k_g<<<dim3(8, 8), 128, 0, stream>>>(P, We, Gt);
    k_scores<<<dim3(S_DIM / CS, B), 512, 0, stream>>>(docIn, Gt, escore, numPart, Zpart);
    k_final<<<B * A_DIM, 128, 0, stream>>>(escore, numPart, Zpart, P, out,
                                           out + (size_t)B * A_DIM * S_DIM);
}